// Round 5
// baseline (69.431 us; speedup 1.0000x reference)
//
#include <hip/hip_runtime.h>

constexpr int N      = 8192;
constexpr int BLK    = 256;
constexpr int CHUNKS = 64;            // y-chunks per direction
constexpr int YC     = N / CHUNKS;    // 128 y-points per chunk (2 KB LDS)
constexpr int P      = 8;             // x-points per thread
constexpr int XG     = N / (BLK * P); // 4 x-groups per direction
constexpr int GRID   = 2 * XG * CHUNKS; // 512 blocks

// Every launch: minbits[0..2N) = 0xFFFFFFFF (+inf pattern ordering), counter = 0.
// Deterministic seed -> the threadfence-counter "last block" test is exact.
__global__ __launch_bounds__(256) void chamfer_init(
    unsigned int* __restrict__ minbits, unsigned int* __restrict__ counter)
{
    int i = blockIdx.x * 256 + threadIdx.x;
    minbits[i] = 0xFFFFFFFFu;
    if (i == 0) *counter = 0u;
}

// Fused: stage y-chunk(+norm) in LDS, register-resident x-points, expansion
// min over chunk, atomicMin(float bits), last block does sqrt+mean -> out[0].
__global__ __launch_bounds__(BLK) void chamfer_fused(
    const float* __restrict__ pred, const float* __restrict__ label,
    unsigned int* __restrict__ minbits,   // 2N uints, init 0xFFFFFFFF
    unsigned int* __restrict__ counter,   // init 0
    float* __restrict__ out)
{
    int b     = blockIdx.x;
    int chunk = b & (CHUNKS - 1);
    int xg    = (b >> 6) & (XG - 1);
    int dir   = b >> 8;

    const float* A = dir ? label : pred;   // query set
    const float* B = dir ? pred  : label;  // target set

    __shared__ float4 sy[YC];
    if (threadIdx.x < YC) {
        int j = chunk * YC + threadIdx.x;
        float a = B[3*j], c = B[3*j+1], d = B[3*j+2];
        sy[threadIdx.x] = make_float4(a, c, d, a*a + c*c + d*d);
    }

    float xa[P], xb[P], xc[P], nx[P], m[P];
    #pragma unroll
    for (int k = 0; k < P; ++k) {
        int idx = xg * (BLK * P) + k * BLK + threadIdx.x;
        float a = A[3*idx], c = A[3*idx+1], d = A[3*idx+2];
        xa[k] = -2.f * a;  xb[k] = -2.f * c;  xc[k] = -2.f * d;
        nx[k] = a*a + c*c + d*d;
        m[k]  = 3.4e38f;
    }
    __syncthreads();

    #pragma unroll 4
    for (int j = 0; j < YC; j += 2) {
        float4 ya = sy[j], yb = sy[j + 1];
        #pragma unroll
        for (int k = 0; k < P; ++k) {
            float sa = fmaf(xa[k], ya.x, fmaf(xb[k], ya.y, fmaf(xc[k], ya.z, ya.w)));
            float sb = fmaf(xa[k], yb.x, fmaf(xb[k], yb.y, fmaf(xc[k], yb.z, yb.w)));
            m[k] = fminf(m[k], fminf(sa, sb));   // v_min3_f32
        }
    }

    #pragma unroll
    for (int k = 0; k < P; ++k) {
        float d2 = fmaxf(m[k] + nx[k], 0.f);     // squared distance, >= 0
        atomicMin(&minbits[dir * N + xg * (BLK * P) + k * BLK + threadIdx.x],
                  __float_as_uint(d2));
    }

    // ---- threadfence reduction: truly-last block finishes the job ----
    __threadfence();               // order this thread's atomics before counter
    __syncthreads();               // all threads' atomics issued
    __shared__ unsigned int isLast;
    if (threadIdx.x == 0) {
        unsigned int old = atomicAdd(counter, 1u);
        isLast = (old == (unsigned int)(GRID - 1)) ? 1u : 0u;  // counter seeded 0
    }
    __syncthreads();
    if (!isLast) return;

    __threadfence();
    float s = 0.f;
    for (int i = threadIdx.x; i < 2 * N; i += BLK) {   // fixed order per thread
        unsigned int ub = __hip_atomic_load(&minbits[i], __ATOMIC_RELAXED,
                                            __HIP_MEMORY_SCOPE_AGENT);
        s += sqrtf(__uint_as_float(ub));
    }
    s *= (1.0f / N);
    for (int off = 32; off; off >>= 1) s += __shfl_down(s, off);
    __shared__ float red[4];
    if ((threadIdx.x & 63) == 0) red[threadIdx.x >> 6] = s;
    __syncthreads();
    if (threadIdx.x == 0)
        out[0] = red[0] + red[1] + red[2] + red[3];   // mean_x(min) + mean_y(min)
}

extern "C" void kernel_launch(void* const* d_in, const int* in_sizes, int n_in,
                              void* d_out, int out_size, void* d_ws, size_t ws_size,
                              hipStream_t stream) {
    const float* pred  = (const float*)d_in[0];
    const float* label = (const float*)d_in[1];
    float* out = (float*)d_out;

    unsigned int* minbits = (unsigned int*)d_ws;            // 2N uints = 64 KB
    unsigned int* counter = minbits + 2 * N;                // 1 uint

    chamfer_init <<<dim3(2 * N / 256), dim3(256), 0, stream>>>(minbits, counter);
    chamfer_fused<<<dim3(GRID), dim3(BLK), 0, stream>>>(pred, label, minbits, counter, out);
}

// Round 6
// 21.767 us; speedup vs baseline: 3.1898x; 3.1898x over previous
//
#include <hip/hip_runtime.h>

constexpr int N    = 8192;
constexpr int BLK  = 256;
constexpr int BX   = 128;      // x-points per block
constexpr int BY   = 2048;     // y-points per block (one y-range)
constexpr int NYR  = N / BY;   // 4 y-ranges
constexpr int P    = 8;        // x-points per thread
constexpr int NSL  = 16;       // y-slices per block
constexpr int SY   = BY / NSL; // 128 y per slice
constexpr int SPAD = SY + 1;   // 129 float4s: slice stride -> +4 banks per slice
constexpr int RPAD = 132;      // red stride: +4 banks per slice

// grid 512: dir = b>>8, xb = (b>>2)&63, yr = b&3.
// Each block: 128 x (complete) x 2048 y (one range). Thread (u = t&15, ys = t>>4)
// owns x {xb*128 + k*16 + u} and scans y-slice ys (128 pts) from LDS.
// Outputs 128 clamped partial-min d2 per block -> minbuf[yr][dir*N + x]. No atomics.
__global__ __launch_bounds__(BLK) void chamfer_stage1(
    const float* __restrict__ pred, const float* __restrict__ label,
    float* __restrict__ minbuf)
{
    int b   = blockIdx.x;
    int dir = b >> 8;
    int xbk = (b >> 2) & 63;
    int yr  = b & 3;

    const float* A = dir ? label : pred;   // query set
    const float* B = dir ? pred  : label;  // target set

    __shared__ float4 sy[NSL * SPAD];      // 33 KB
    __shared__ float  red[NSL * RPAD];     // 8.25 KB

    int u  = threadIdx.x & 15;
    int ys = threadIdx.x >> 4;

    // register-resident x fragments (issued before the barrier, overlap staging)
    float xa[P], xb[P], xc[P], nx[P], m[P];
    #pragma unroll
    for (int k = 0; k < P; ++k) {
        int idx = xbk * BX + k * 16 + u;
        float a = A[3*idx], c = A[3*idx+1], d = A[3*idx+2];
        xa[k] = -2.f * a;  xb[k] = -2.f * c;  xc[k] = -2.f * d;
        nx[k] = a*a + c*c + d*d;
        m[k]  = 3.4e38f;
    }

    // stage y-range (+norm) into padded LDS slices
    for (int i = threadIdx.x; i < BY; i += BLK) {
        int g = yr * BY + i;
        float a = B[3*g], c = B[3*g+1], d = B[3*g+2];
        sy[(i >> 7) * SPAD + (i & (SY-1))] = make_float4(a, c, d, a*a + c*c + d*d);
    }
    __syncthreads();

    const float4* s = &sy[ys * SPAD];
    #pragma unroll 4
    for (int j = 0; j < SY; j += 2) {
        float4 ya = s[j], yb = s[j + 1];
        #pragma unroll
        for (int k = 0; k < P; ++k) {
            float sa = fmaf(xa[k], ya.x, fmaf(xb[k], ya.y, fmaf(xc[k], ya.z, ya.w)));
            float sb = fmaf(xa[k], yb.x, fmaf(xb[k], yb.y, fmaf(xc[k], yb.z, yb.w)));
            m[k] = fminf(m[k], fminf(sa, sb));   // v_min3_f32
        }
    }

    // per-slice clamped partial d2 -> red, then 16-way slice combine
    #pragma unroll
    for (int k = 0; k < P; ++k)
        red[ys * RPAD + k * 16 + u] = fmaxf(m[k] + nx[k], 0.f);
    __syncthreads();

    if (threadIdx.x < BX) {
        float v = red[threadIdx.x];
        #pragma unroll
        for (int q = 1; q < NSL; ++q)
            v = fminf(v, red[q * RPAD + threadIdx.x]);
        minbuf[yr * (2 * N) + dir * N + xbk * BX + threadIdx.x] = v;
    }
}

// One 1024-thread block: min over 4 y-ranges (coalesced), sqrt, fixed-order mean.
__global__ __launch_bounds__(1024) void chamfer_stage2(
    const float* __restrict__ minbuf, float* __restrict__ out)
{
    float s = 0.f;
    #pragma unroll
    for (int j = 0; j < (2 * N) / 1024; ++j) {          // 16 iters
        int g = j * 1024 + threadIdx.x;
        float v =          minbuf[            g];
        v = fminf(v,       minbuf[1 * 2*N +   g]);
        v = fminf(v,       minbuf[2 * 2*N +   g]);
        v = fminf(v,       minbuf[3 * 2*N +   g]);
        s += sqrtf(v);
    }
    s *= (1.0f / N);
    for (int off = 32; off; off >>= 1) s += __shfl_down(s, off);
    __shared__ float r2[16];
    if ((threadIdx.x & 63) == 0) r2[threadIdx.x >> 6] = s;
    __syncthreads();
    if (threadIdx.x == 0) {
        float v = 0.f;
        #pragma unroll
        for (int i = 0; i < 16; ++i) v += r2[i];
        out[0] = v;            // mean_x(min) + mean_y(min)
    }
}

extern "C" void kernel_launch(void* const* d_in, const int* in_sizes, int n_in,
                              void* d_out, int out_size, void* d_ws, size_t ws_size,
                              hipStream_t stream) {
    const float* pred  = (const float*)d_in[0];
    const float* label = (const float*)d_in[1];
    float* out    = (float*)d_out;
    float* minbuf = (float*)d_ws;   // NYR * 2N floats = 256 KB, fully rewritten each launch

    chamfer_stage1<<<dim3(2 * (N / BX) * NYR), dim3(BLK),  0, stream>>>(pred, label, minbuf);
    chamfer_stage2<<<dim3(1),                  dim3(1024), 0, stream>>>(minbuf, out);
}